// Round 17
// baseline (110.211 us; speedup 1.0000x reference)
//
#include <hip/hip_runtime.h>
#include <hip/hip_bf16.h>

// Problem constants
constexpr int BATCH = 4096;
constexpr int IN    = 512;
constexpr int OUT   = 512;
constexpr int ORD   = 8;
constexpr int NK    = ORD + 1;        // 9
constexpr float FA  = 1.0f, FB = 1.0f;

// GEMM inner dim EXCLUDES k=0 (J0 == 1 -> bias term), KP = 4096.
// K-ORDERING (new, i-major): K = i*8 + (n-1). One k-octet (quad,j) of an
// MFMA fragment = one i's 8 orders -> a single thread computes tanh+recurrence
// and emits one 16B LDS entry. ks-tile = 32 K = 4 i's; z covers i in
// [z*128, z*128+128).
constexpr int KP     = IN * ORD;
constexpr int SPLITK = 4;                      // 512 blocks -> 2 blocks/CU
constexpr int KT     = KP / (32 * SPLITK);     // 32 K-steps per block
constexpr int KS_TOT = KP / 32;                // 128 k-steps total

typedef __attribute__((ext_vector_type(8))) short short8;   // 8 bf16
typedef __attribute__((ext_vector_type(4))) float floatx4;  // MFMA C/D

__device__ __forceinline__ float bf16bits_to_f32(short s) {
    union { unsigned int u; float f; } cv;
    cv.u = ((unsigned int)(unsigned short)s) << 16;
    return cv.f;
}
__device__ __forceinline__ short f32_to_bf16bits(float f) {
    __hip_bfloat16 h = __float2bfloat16(f);
    return *(short*)&h;
}

// ---------------------------------------------------------------------------
// Kernel 1 (prep, 256 blocks — Jacobi branch is GONE, fused into gemm):
//  blocks [0,128):   B2[nt][ks] line: lane(quad,l15) holds
//                    coeff[o=nt*16+l15][i=ks*4+quad][n=1..8] * w[o][i]
//  blocks [128,256): bias[o] = sum_i coeff[o,i,0]*w[o,i] (1 wave per o)
// ---------------------------------------------------------------------------
__global__ __launch_bounds__(256) void prep(const float* __restrict__ wm,
                                            const float* __restrict__ coeff,
                                            short* __restrict__ B2,
                                            float* __restrict__ bias) {
    const int bid  = blockIdx.x;
    const int tid  = threadIdx.x;
    const int lane = tid & 63;
    const int quad = lane >> 4;
    const int l15  = lane & 15;
    const int wv   = tid >> 6;

    if (bid < 128) {
        const int nt  = bid >> 2;
        const int ksb = (bid & 3) * 32 + wv * 8;         // 8 lines per wave
        const int o   = nt * 16 + l15;
#pragma unroll
        for (int c = 0; c < 8; ++c) {
            const int ks = ksb + c;
            const int i  = ks * 4 + quad;
            const float ww = wm[(size_t)o * IN + i];
            const float* cf = coeff + ((size_t)o * IN + i) * NK;
            short8 v;
#pragma unroll
            for (int e = 0; e < 8; ++e)
                v[e] = f32_to_bf16bits(cf[1 + e] * ww);
            *(short8*)(B2 + (((size_t)nt * KS_TOT + ks) * 64 + lane) * 8) = v;
        }
    } else {
        // ---- bias branch: 128 blocks, one wave per output o ----
        const int bb = bid - 128;                        // 0..127
        const int o  = bb * 4 + wv;
        const float* cf = coeff + (size_t)o * IN * NK;
        const float* wr = wm + (size_t)o * IN;
        float acc = 0.0f;
#pragma unroll
        for (int r = 0; r < IN / 64; ++r) {
            int i = r * 64 + lane;
            acc = fmaf(cf[(size_t)i * NK], wr[i], acc);
        }
#pragma unroll
        for (int off = 32; off >= 1; off >>= 1)
            acc += __shfl_xor(acc, off, 64);
        if (lane == 0) bias[o] = acc;
    }
}

// ---------------------------------------------------------------------------
// Kernel 2: FUSED split-K GEMM — A computed in-kernel (no A2 tensor at all).
// Per 4-step batch: threads compute J for 2048 (b,i) tasks (8/thread:
// x-load -> tanh -> order recurrence -> one ds_write_b128) into a
// double-buffered LDS A-tile; B direct from L1 via r11's 2-slot register
// pipeline; one barrier per batch (r16 skeleton).
// Removes: 33.5 MB A2 cold HBM fetch + prep's Jacobi branch.
// ---------------------------------------------------------------------------
__global__ __launch_bounds__(256, 2) void gemm_fused(
        const float* __restrict__ x,    // [4096][512]
        const short* __restrict__ B2,   // [32][128] x 1KB lines
        __hip_bfloat16* __restrict__ P) // [SPLITK][4096][512] bf16
{
    __shared__ short sA[2 * 32 * 512];  // 2 buf x 32 lines x 1KB = 64 KB

    const int tid  = threadIdx.x;
    const int lane = tid & 63;
    const int quad = lane >> 4;
    const int l15  = lane & 15;
    const int wv   = tid >> 6;
    const int mw   = (tid >> 6) & 1;
    const int nw   = tid >> 7;
    const int bx = blockIdx.x;          // 0..31  (m-tiles of 128)
    const int by = blockIdx.y;          // 0..3   (n-tiles of 128)
    const int z  = blockIdx.z;          // 0..3

    const short* pb[4];
#pragma unroll
    for (int j = 0; j < 4; ++j)
        pb[j] = B2 + (((size_t)(by * 8 + nw * 4 + j) * KS_TOT + z * KT) * 64 + lane) * 8;

    floatx4 acc[4][4];
#pragma unroll
    for (int i = 0; i < 4; ++i)
#pragma unroll
        for (int j = 0; j < 4; ++j) acc[i][j] = (floatx4)0.0f;

    // task c (0..7): line ll = c*4 + wv; s = ll>>3 (step), mt = ll&7 (m-line)
    // b = bx*128 + mt*16 + l15 ; i = (z*32 + bt*4 + s)*4 + quad
#define XLOAD(BT, XV)                                                        \
    _Pragma("unroll")                                                        \
    for (int c = 0; c < 8; ++c) {                                            \
        const int ll = c * 4 + wv;                                           \
        const int s  = ll >> 3;                                              \
        const int mt = ll & 7;                                               \
        XV[c] = x[(size_t)(bx * 128 + mt * 16 + l15) * IN +                  \
                  ((z * 32 + (BT) * 4 + s) * 4 + quad)];                     \
    }

#define JCOMP(XV, BUF)                                                       \
    _Pragma("unroll")                                                        \
    for (int c = 0; c < 8; ++c) {                                            \
        const int ll = c * 4 + wv;                                           \
        float xc = fminf(fmaxf(XV[c], -9.0f), 9.0f);                         \
        float ex = __expf(2.0f * xc);                                        \
        float t  = (ex - 1.0f) / (ex + 1.0f);                                \
        float p0 = 1.0f, p1 = 2.0f * t;   /* a=b=1: J1 = 2t */               \
        short8 v;                                                            \
        v[0] = f32_to_bf16bits(p1);                                          \
        _Pragma("unroll")                                                    \
        for (int n = 2; n <= ORD; ++n) {                                     \
            float fn = (float)n;                                             \
            float k1 = (2.f*fn+FA+FB)*(2.f*fn+FA+FB-1.f)/(2.f*fn*(fn+FA+FB));\
            float k2 = (2.f*fn+FA+FB-1.f)*(FA*FA-FB*FB) /                    \
                       (2.f*fn*(fn+FA+FB)*(2.f*fn+FA+FB-2.f));               \
            float k3 = (fn+FA-1.f)*(fn+FB-1.f)*(2.f*fn+FA+FB) /              \
                       (fn*(fn+FA+FB)*(2.f*fn+FA+FB-2.f));                   \
            float p2 = (k1*t + k2)*p1 - k3*p0;                               \
            v[n - 1] = f32_to_bf16bits(p2);                                  \
            p0 = p1; p1 = p2;                                                \
        }                                                                    \
        *(short8*)(sA + (BUF) * 16384 + ll * 512 + lane * 8) = v;            \
    }

#define ASTEP(BUF, S, BSLOT, KREF, DOREF)                                    \
    {                                                                        \
        short8 af[4];                                                        \
        _Pragma("unroll")                                                    \
        for (int i = 0; i < 4; ++i)                                          \
            af[i] = *(const short8*)(sA + (BUF) * 16384 +                    \
                        ((S) * 8 + mw * 4 + i) * 512 + lane * 8);            \
        _Pragma("unroll")                                                    \
        for (int i = 0; i < 4; ++i)                                          \
            _Pragma("unroll")                                                \
            for (int j = 0; j < 4; ++j)                                      \
                acc[i][j] = __builtin_amdgcn_mfma_f32_16x16x32_bf16(         \
                                af[i], BSLOT[j], acc[i][j], 0, 0, 0);        \
        if (DOREF) {                                                         \
            _Pragma("unroll")                                                \
            for (int j = 0; j < 4; ++j)                                      \
                BSLOT[j] = *(const short8*)(pb[j] + (KREF) * 512);           \
        }                                                                    \
    }

    // B 2-slot preload (k = 0, 1)
    short8 bs0[4], bs1[4];
#pragma unroll
    for (int j = 0; j < 4; ++j) { bs0[j] = *(const short8*)(pb[j]);
                                  bs1[j] = *(const short8*)(pb[j] + 512); }

    // prologue: compute batch 0 into buf 0
    float xv[8];
    XLOAD(0, xv)
    JCOMP(xv, 0)
    __syncthreads();

    for (int bt = 0; bt < 7; ++bt) {
        const int buf = bt & 1;
        XLOAD(bt + 1, xv)               // loads land during the 4 MFMA steps
        const int k0 = bt * 4;
        ASTEP(buf, 0, bs0, k0 + 2, true)
        ASTEP(buf, 1, bs1, k0 + 3, true)
        ASTEP(buf, 2, bs0, k0 + 4, true)
        ASTEP(buf, 3, bs1, k0 + 5, true)
        JCOMP(xv, buf ^ 1)              // VALU overlaps co-wave MFMA (m114)
        __syncthreads();                // buf^1 ready; reads of buf done
    }
    // batch 7 (buf 1): k = 28,29 refill 30,31; k = 30,31 no refill
    ASTEP(1, 0, bs0, 30, true)
    ASTEP(1, 1, bs1, 31, true)
    ASTEP(1, 2, bs0, 0, false)
    ASTEP(1, 3, bs1, 0, false)

#undef ASTEP
#undef JCOMP
#undef XLOAD

    // epilogue: C/D layout col = lane&15, row = quad*4 + reg; bf16 partials
    __hip_bfloat16* Pz = P + (size_t)z * BATCH * OUT;
    const int m0 = bx * 128, n0 = by * 128;
#pragma unroll
    for (int i = 0; i < 4; ++i) {
        const int r0 = m0 + mw * 64 + i * 16 + quad * 4;
#pragma unroll
        for (int j = 0; j < 4; ++j) {
            const int c = n0 + nw * 64 + j * 16 + l15;
#pragma unroll
            for (int r = 0; r < 4; ++r)
                Pz[(size_t)(r0 + r) * OUT + c] = __float2bfloat16(acc[i][j][r]);
        }
    }
}

// ---------------------------------------------------------------------------
// Kernel 3: out[b,o] = sum_z P[z][b,o] + bias[o]   (8 outputs per thread)
// ---------------------------------------------------------------------------
__global__ __launch_bounds__(256) void reducek(const short* __restrict__ P,
                                               const float* __restrict__ bias,
                                               float* __restrict__ out) {
    const int j = blockIdx.x * 256 + threadIdx.x;
    const size_t base = (size_t)j * 8;
    constexpr size_t PLANE = (size_t)BATCH * OUT;

    float s[8];
    {
        short8 v = *(const short8*)(P + base);
#pragma unroll
        for (int e = 0; e < 8; ++e) s[e] = bf16bits_to_f32(v[e]);
    }
#pragma unroll
    for (int z = 1; z < SPLITK; ++z) {
        short8 v = *(const short8*)(P + z * PLANE + base);
#pragma unroll
        for (int e = 0; e < 8; ++e) s[e] += bf16bits_to_f32(v[e]);
    }
    const int o0 = (int)(base & (OUT - 1));
    const floatx4 b0 = *(const floatx4*)(bias + o0);
    const floatx4 b1 = *(const floatx4*)(bias + o0 + 4);
    floatx4 r0 = {s[0] + b0[0], s[1] + b0[1], s[2] + b0[2], s[3] + b0[3]};
    floatx4 r1 = {s[4] + b1[0], s[5] + b1[1], s[6] + b1[2], s[7] + b1[3]};
    *(floatx4*)(out + base)     = r0;
    *(floatx4*)(out + base + 4) = r1;
}

// ---------------------------------------------------------------------------
extern "C" void kernel_launch(void* const* d_in, const int* in_sizes, int n_in,
                              void* d_out, int out_size, void* d_ws, size_t ws_size,
                              hipStream_t stream) {
    const float* x     = (const float*)d_in[0];   // [4096,512]
    const float* w     = (const float*)d_in[1];   // [512,512]
    const float* coeff = (const float*)d_in[2];   // [512,512,9]
    float* out = (float*)d_out;                   // [4096,512]

    // workspace layout (bytes) — no A2 anymore
    char* ws = (char*)d_ws;
    short* B2 = (short*)ws;                                            //  4,194,304 B
    char* p1c = ws + (size_t)OUT * KP * 2;
    __hip_bfloat16* P = (__hip_bfloat16*)p1c;                          // 16,777,216 B
    float* bias = (float*)(p1c + (size_t)SPLITK * BATCH * OUT * 2);    //      2,048 B

    prep<<<256, 256, 0, stream>>>(w, coeff, B2, bias);
    gemm_fused<<<dim3(32, 4, SPLITK), 256, 0, stream>>>(x, B2, P);
    reducek<<<BATCH * OUT / 8 / 256, 256, 0, stream>>>((const short*)P, bias, out);
}